// Round 10
// baseline (1712.141 us; speedup 1.0000x reference)
//
#include <hip/hip_runtime.h>
#include <hip/hip_bf16.h>
#include <math.h>

#define NODE 90
#define HID 256
#define NB 512
#define NN (NB * NODE)
#define EDGES (NB * 2700)

__device__ __forceinline__ float tanh_safe(float s) {
    s = fminf(fmaxf(s, -15.f), 15.f);
    float t = __expf(2.f * s);
    return (t - 1.f) / (t + 1.f);
}

// ---------------------------------------------------------------------------
// Module-scope fp32 scratch (~316 MB .bss). d_ws unused.
// ---------------------------------------------------------------------------
__device__ float g_adjS[(size_t)NB * NODE * NODE];
__device__ float g_adjF[(size_t)NB * NODE * NODE];
__device__ float g_T[(size_t)2 * NN * HID];          // 2N rows (S then F)
__device__ float g_hs[(size_t)NN * HID];
__device__ float g_hf[(size_t)NN * HID];
__device__ float g_cs[(size_t)NN * HID];
__device__ float g_cf[(size_t)NN * HID];
__device__ int g_flags[2];

__device__ __forceinline__ float* adjPtr(int w) { return w ? g_adjF : g_adjS; }
__device__ __forceinline__ float* selbuf(int w) {
    switch (w) {
        case 0: return g_hs;
        case 1: return g_hf;
        case 2: return g_cs;
        default: return g_cf;
    }
}

// ---------------------------------------------------------------------------
__global__ void k_detect(const void* edges) {
    if (threadIdx.x != 0 || blockIdx.x != 0) return;
    const int* ei = (const int*)edges;
    int odd_nonzero = 0;
    for (int i = 0; i < 2048; i += 2)
        if (ei[i + 1] != 0) odd_nonzero = 1;
    g_flags[1] = odd_nonzero ? 0 : 1;
}

__global__ void k_zero_adj() {
    size_t n = (size_t)NB * NODE * NODE;
    size_t stride = (size_t)gridDim.x * blockDim.x;
    for (size_t i = (size_t)blockIdx.x * blockDim.x + threadIdx.x; i < n; i += stride) {
        g_adjS[i] = 0.f;
        g_adjF[i] = 0.f;
    }
}

// ---------------------------------------------------------------------------
__global__ void k_build_adj(const void* __restrict__ edges, int which) {
    float* adj = adjPtr(which);
    int e64 = g_flags[1];
    const int* e32 = (const int*)edges;
    const long long* e64p = (const long long*)edges;
    int i = blockIdx.x * blockDim.x + threadIdx.x;
    int stride = gridDim.x * blockDim.x;
    for (; i < EDGES; i += stride) {
        long long s, d;
        if (e64) { s = e64p[i]; d = e64p[EDGES + i]; }
        else     { s = e32[i];  d = e32[EDGES + i]; }
        if (s < 0 || s >= NN || d < 0 || d >= NN) continue;
        int b = (int)(d / NODE);
        if ((int)(s / NODE) != b) continue;
        atomicAdd(&adj[(size_t)b * NODE * NODE +
                       (size_t)((int)d - b * NODE) * NODE + ((int)s - b * NODE)], 1.0f);
    }
}

// ---------------------------------------------------------------------------
__global__ void k_norm_adj(int which) {
    float* A = adjPtr(which) + (size_t)blockIdx.x * NODE * NODE;
    __shared__ float dinv[NODE];
    int tid = threadIdx.x;
    if (tid < NODE) {
        float s = 0.f;
        for (int k = 0; k < NODE; k++) s += A[tid * NODE + k];
        dinv[tid] = (s > 0.f) ? rsqrtf(s) : 0.f;
    }
    __syncthreads();
    for (int i = tid; i < NODE * NODE; i += blockDim.x) {
        int d = i / NODE;
        int s = i - d * NODE;
        A[i] *= dinv[d] * dinv[s];
    }
}

// ---------------------------------------------------------------------------
// Fused two-stream tiled GEMM: g_T[row][c] = X(row) @ W.
// Rows [0, rbPerSide*128) use side A, rest side B. Per side, X is either an
// external ptr (ldx_ext) or selbuf(s1) [+ selbuf(s2) as cols 256.. for K=512].
// 128x128 tile, BK=16, 256 thr, 8x8 micro-tile.  T14 reg-staged prefetch;
// As stored staggered (col r -> r + 4*(r>>5), stride 140) => 2-way banks.
// ---------------------------------------------------------------------------
#define BM 128
#define BN 128
#define BKc 16
#define ASTR 140
__global__ __launch_bounds__(256) void k_gemm_tile(
    const float* __restrict__ XA, const float* __restrict__ XB,
    int sA1, int sA2, int sB1, int sB2,
    int K, int ldx_ext, const float* __restrict__ W, int rbPerSide) {
    __shared__ float As[BKc][ASTR];
    __shared__ float Bs[BKc][BN + 4];
    int tid = threadIdx.x;
    int id = blockIdx.x;
    int bm = id >> 1, bn = id & 1;
    int side = (bm >= rbPerSide) ? 1 : 0;
    int bmL = bm - side * rbPerSide;
    int r0 = bmL * BM;               // row base within side's X
    int r0g = bm * BM;               // row base in g_T
    int c0 = bn * BN;
    const float* Xe = side ? XB : XA;
    int s1 = side ? sB1 : sA1;
    int s2 = side ? sB2 : sA2;
    const float* X1 = (s1 >= 0) ? selbuf(s1) : Xe;
    const float* X2 = (s2 >= 0) ? selbuf(s2) : nullptr;
    int ldx = (s1 >= 0) ? HID : ldx_ext;

    int ti = tid & 15, tj = tid >> 4;
    int nt = (K + BKc - 1) >> 4;

    float ra[8];
    float4 rb[2];
    float acc[8][8];
#pragma unroll
    for (int i = 0; i < 8; i++)
#pragma unroll
        for (int j = 0; j < 8; j++) acc[i][j] = 0.f;

#define LOAD_TILE(T_)                                                         \
    {                                                                         \
        int k0 = (T_) << 4;                                                   \
        int kl = K - k0; if (kl > BKc) kl = BKc;                              \
        const float* Xs; int xc;                                              \
        if (s2 >= 0 && k0 >= HID) { Xs = X2; xc = k0 - HID; }                 \
        else                      { Xs = X1; xc = k0; }                       \
        _Pragma("unroll")                                                     \
        for (int q = 0; q < 8; q++) {                                         \
            int i_ = tid + (q << 8);                                          \
            int r_ = i_ >> 4, kk_ = i_ & 15;                                  \
            ra[q] = (kk_ < kl) ? Xs[(size_t)(r0 + r_) * ldx + xc + kk_] : 0.f;\
        }                                                                     \
        _Pragma("unroll")                                                     \
        for (int q = 0; q < 2; q++) {                                         \
            int i_ = tid + (q << 8);                                          \
            int kk_ = i_ >> 5, c4_ = (i_ & 31) << 2;                          \
            rb[q] = (kk_ < kl) ? *(const float4*)&W[(size_t)(k0 + kk_) * HID + c0 + c4_] \
                               : make_float4(0.f, 0.f, 0.f, 0.f);             \
        }                                                                     \
    }
#define WRITE_TILE()                                                          \
    {                                                                         \
        _Pragma("unroll")                                                     \
        for (int q = 0; q < 8; q++) {                                         \
            int i_ = tid + (q << 8);                                          \
            int r_ = i_ >> 4, kk_ = i_ & 15;                                  \
            As[kk_][r_ + 4 * (r_ >> 5)] = ra[q];                              \
        }                                                                     \
        _Pragma("unroll")                                                     \
        for (int q = 0; q < 2; q++) {                                         \
            int i_ = tid + (q << 8);                                          \
            int kk_ = i_ >> 5, c4_ = (i_ & 31) << 2;                          \
            *(float4*)&Bs[kk_][c4_] = rb[q];                                  \
        }                                                                     \
    }

    LOAD_TILE(0);
    WRITE_TILE();
    int abase = 8 * ti + ((ti >> 2) << 2);
    for (int t = 0; t < nt; t++) {
        __syncthreads();                    // tile t visible in LDS
        if (t + 1 < nt) LOAD_TILE(t + 1);   // prefetch under compute
#pragma unroll
        for (int kk = 0; kk < BKc; kk++) {
            float4 a0 = *(const float4*)&As[kk][abase];
            float4 a1 = *(const float4*)&As[kk][abase + 4];
            float4 b0 = *(const float4*)&Bs[kk][8 * tj];
            float4 b1 = *(const float4*)&Bs[kk][8 * tj + 4];
            float av[8] = {a0.x, a0.y, a0.z, a0.w, a1.x, a1.y, a1.z, a1.w};
            float bv[8] = {b0.x, b0.y, b0.z, b0.w, b1.x, b1.y, b1.z, b1.w};
#pragma unroll
            for (int i = 0; i < 8; i++)
#pragma unroll
                for (int j = 0; j < 8; j++)
                    acc[i][j] = fmaf(av[i], bv[j], acc[i][j]);
        }
        if (t + 1 < nt) {
            __syncthreads();                // all reads of tile t done
            WRITE_TILE();                   // overwrite with tile t+1
        }
    }

#pragma unroll
    for (int i = 0; i < 8; i++) {
        size_t r = (size_t)(r0g + 8 * ti + i);
        float4 o0 = make_float4(acc[i][0], acc[i][1], acc[i][2], acc[i][3]);
        float4 o1 = make_float4(acc[i][4], acc[i][5], acc[i][6], acc[i][7]);
        *(float4*)&g_T[r * HID + c0 + 8 * tj] = o0;
        *(float4*)&g_T[r * HID + c0 + 8 * tj + 4] = o1;
    }
#undef LOAD_TILE
#undef WRITE_TILE
}

// ---------------------------------------------------------------------------
// Fused two-stream aggregate. grid = 2048: side = idx>=1024, graph = (idx&1023)>>1,
// col-half = idx&1.  out = relu(Adj @ T + bias) -> selbuf(hsel0+side) + out x-cols.
// ---------------------------------------------------------------------------
__global__ __launch_bounds__(256) void k_agg2(const float* __restrict__ bias,
                                              int hsel0, float* __restrict__ outS,
                                              float* __restrict__ outF) {
    __shared__ float AdjT[NODE][102];
    int tid = threadIdx.x;
    int idx = blockIdx.x;
    int side = idx >> 10;
    int b = (idx & 1023) >> 1;
    int c0 = (idx & 1) * 128;
    const float* Adj = adjPtr(side) + (size_t)b * NODE * NODE;
    const float* Tg = g_T + ((size_t)side * NN + (size_t)b * NODE) * HID;
    float* outp = side ? outF : outS;
    float* hdst = selbuf(hsel0 + side);

    for (int i = tid; i < NODE * NODE; i += 256) {
        int n = i / NODE, k = i - n * NODE;
        AdjT[k][n] = Adj[i];
    }
    for (int i = tid; i < NODE * 12; i += 256) {
        int k = i / 12, n = NODE + (i % 12);
        AdjT[k][n] = 0.f;
    }
    __syncthreads();

    int ti = tid & 15, tj = tid >> 4;
    int rbase = 6 * ti;
    int cc = c0 + 8 * tj;

    float acc[6][8];
#pragma unroll
    for (int i = 0; i < 6; i++)
#pragma unroll
        for (int j = 0; j < 8; j++) acc[i][j] = 0.f;

#pragma unroll 2
    for (int k = 0; k < NODE; k++) {
        float4 t0 = *(const float4*)&Tg[(size_t)k * HID + cc];
        float4 t1 = *(const float4*)&Tg[(size_t)k * HID + cc + 4];
        float bv[8] = {t0.x, t0.y, t0.z, t0.w, t1.x, t1.y, t1.z, t1.w};
        float2 a01 = *(const float2*)&AdjT[k][rbase];
        float2 a23 = *(const float2*)&AdjT[k][rbase + 2];
        float2 a45 = *(const float2*)&AdjT[k][rbase + 4];
        float av[6] = {a01.x, a01.y, a23.x, a23.y, a45.x, a45.y};
#pragma unroll
        for (int i = 0; i < 6; i++)
#pragma unroll
            for (int j = 0; j < 8; j++)
                acc[i][j] = fmaf(av[i], bv[j], acc[i][j]);
    }

    float bb[8];
#pragma unroll
    for (int j = 0; j < 8; j++) bb[j] = bias[cc + j];

#pragma unroll
    for (int i = 0; i < 6; i++) {
        int n = rbase + i;
        if (n < NODE) {
            size_t row = (size_t)(b * NODE + n);
            float v[8];
#pragma unroll
            for (int j = 0; j < 8; j++) v[j] = fmaxf(acc[i][j] + bb[j], 0.f);
            float4 o0 = make_float4(v[0], v[1], v[2], v[3]);
            float4 o1 = make_float4(v[4], v[5], v[6], v[7]);
            *(float4*)&hdst[row * HID + cc] = o0;
            *(float4*)&hdst[row * HID + cc + 4] = o1;
            *(float4*)&outp[row * 512 + cc] = o0;
            *(float4*)&outp[row * 512 + cc + 4] = o1;
        }
    }
}

// ---------------------------------------------------------------------------
// Fused co-attention per graph (unchanged from round 9 — verified).
// ---------------------------------------------------------------------------
#define CO_THREADS 512
__global__ __launch_bounds__(CO_THREADS, 1) void k_coatt(int hfsel, int hssel,
                                                         float* __restrict__ outS,
                                                         float* __restrict__ outF,
                                                         int cssel, int cfsel) {
    __shared__ float hfl[NODE][258];
    __shared__ float Pm[NODE][92];
    __shared__ float t2s[NODE][34];
    __shared__ float rmax_[NODE], rinv_[NODE], fn_[NODE], gm_[NODE];

    int b = blockIdx.x;
    int tid = threadIdx.x;
    const float* HF = selbuf(hfsel) + (size_t)b * NODE * HID;
    const float* HS = selbuf(hssel) + (size_t)b * NODE * HID;
    const float* T2 = g_T + (size_t)b * NODE * HID;

    for (int i = tid; i < NODE * 64; i += CO_THREADS) {
        int n = i >> 6, c4 = (i & 63) << 2;
        *(float4*)&hfl[n][c4] = *(const float4*)&HF[(size_t)n * HID + c4];
    }

    {
        const int tm = tid & 31;
        const int tn5 = tid >> 5;
        const float* hr0 = hfl[tm];
        const float* hr1 = hfl[tm + 32];
        const float* hr2 = hfl[(tm < 26) ? tm + 64 : 0];
        const float* tr[6];
#pragma unroll
        for (int k = 0; k < 6; k++) {
            int n = tn5 + 16 * k;
            tr[k] = t2s[(n < NODE) ? n : 0];
        }
        float at[3][6];
#pragma unroll
        for (int i = 0; i < 3; i++)
#pragma unroll
            for (int k = 0; k < 6; k++) at[i][k] = 0.f;

        for (int d0 = 0; d0 < HID; d0 += 32) {
            __syncthreads();
            for (int i = tid; i < NODE * 32; i += CO_THREADS) {
                int n = i >> 5, dd = i & 31;
                t2s[n][dd] = T2[(size_t)n * HID + d0 + dd];
            }
            __syncthreads();
#pragma unroll
            for (int dd = 0; dd < 32; dd += 2) {
                float2 a0 = *(const float2*)&hr0[d0 + dd];
                float2 a1 = *(const float2*)&hr1[d0 + dd];
                float2 a2 = *(const float2*)&hr2[d0 + dd];
#pragma unroll
                for (int k = 0; k < 6; k++) {
                    float2 bk = *(const float2*)&tr[k][dd];
                    at[0][k] = fmaf(a0.x, bk.x, at[0][k]);
                    at[0][k] = fmaf(a0.y, bk.y, at[0][k]);
                    at[1][k] = fmaf(a1.x, bk.x, at[1][k]);
                    at[1][k] = fmaf(a1.y, bk.y, at[1][k]);
                    at[2][k] = fmaf(a2.x, bk.x, at[2][k]);
                    at[2][k] = fmaf(a2.y, bk.y, at[2][k]);
                }
            }
        }
        __syncthreads();
        int mv[3] = {tm, tm + 32, tm + 64};
#pragma unroll
        for (int i = 0; i < 3; i++) {
            if (mv[i] < NODE) {
#pragma unroll
                for (int k = 0; k < 6; k++) {
                    int n = tn5 + 16 * k;
                    if (n < NODE) Pm[n][mv[i]] = tanh_safe(at[i][k]);
                }
            }
        }
    }
    __syncthreads();

    if (tid < NODE) {
        int n = tid;
        float mx = -2.f;
        for (int m = 0; m < NODE; m++) mx = fmaxf(mx, Pm[n][m]);
        float s = 0.f;
        for (int m = 0; m < NODE; m++) s += __expf(Pm[n][m] - mx);
        rmax_[n] = mx;
        rinv_[n] = 1.f / s;
        fn_[n] = s * __expf(mx);
    } else if (tid >= 256 && tid < 256 + NODE) {
        int m = tid - 256;
        float mx = -2.f;
        for (int n = 0; n < NODE; n++) mx = fmaxf(mx, Pm[n][m]);
        float s = 0.f;
        for (int n = 0; n < NODE; n++) s += __expf(Pm[n][m] - mx);
        gm_[m] = __expf(-mx) / s;
    }
    __syncthreads();

    for (int i = tid; i < NODE * NODE; i += CO_THREADS) {
        int n = i / NODE, m = i - n * NODE;
        Pm[n][m] = __expf(Pm[n][m] - rmax_[n]) * rinv_[n];
    }
    __syncthreads();

    {
        const int tc4 = (tid & 63) << 2;
        const int tnn = tid >> 6;
        int nrow[12];
#pragma unroll
        for (int k = 0; k < 12; k++) {
            int n = tnn + 8 * k;
            nrow[k] = (n < NODE) ? n : 0;
        }
        float acc[12][4];
#pragma unroll
        for (int k = 0; k < 12; k++)
#pragma unroll
            for (int j = 0; j < 4; j++) acc[k][j] = 0.f;

#pragma unroll 2
        for (int m = 0; m < NODE; m++) {
            float4 h = *(const float4*)&hfl[m][tc4];
#pragma unroll
            for (int k = 0; k < 12; k++) {
                float p = Pm[nrow[k]][m];
                acc[k][0] = fmaf(p, h.x, acc[k][0]);
                acc[k][1] = fmaf(p, h.y, acc[k][1]);
                acc[k][2] = fmaf(p, h.z, acc[k][2]);
                acc[k][3] = fmaf(p, h.w, acc[k][3]);
            }
        }
        float* cs = selbuf(cssel);
#pragma unroll
        for (int k = 0; k < 12; k++) {
            int n = tnn + 8 * k;
            if (n < NODE) {
                size_t row = (size_t)(b * NODE + n);
                float4 o = make_float4(acc[k][0], acc[k][1], acc[k][2], acc[k][3]);
                *(float4*)&outS[row * 512 + tc4] = o;
                *(float4*)&cs[row * HID + tc4] = o;
            }
        }
    }
    __syncthreads();

    for (int i = tid; i < NODE * 64; i += CO_THREADS) {
        int n = i >> 6, c4 = (i & 63) << 2;
        *(float4*)&hfl[n][c4] = *(const float4*)&HS[(size_t)n * HID + c4];
    }
    for (int i = tid; i < NODE * NODE; i += CO_THREADS) {
        int n = i / NODE, m = i - n * NODE;
        Pm[n][m] *= fn_[n];
    }
    __syncthreads();

    {
        const int tc4 = (tid & 63) << 2;
        const int tmm = tid >> 6;
        int mrow[12];
#pragma unroll
        for (int k = 0; k < 12; k++) {
            int m = tmm + 8 * k;
            mrow[k] = (m < NODE) ? m : 0;
        }
        float acc[12][4];
#pragma unroll
        for (int k = 0; k < 12; k++)
#pragma unroll
            for (int j = 0; j < 4; j++) acc[k][j] = 0.f;

#pragma unroll 2
        for (int n = 0; n < NODE; n++) {
            float4 h = *(const float4*)&hfl[n][tc4];
#pragma unroll
            for (int k = 0; k < 12; k++) {
                float p = Pm[n][mrow[k]];
                acc[k][0] = fmaf(p, h.x, acc[k][0]);
                acc[k][1] = fmaf(p, h.y, acc[k][1]);
                acc[k][2] = fmaf(p, h.z, acc[k][2]);
                acc[k][3] = fmaf(p, h.w, acc[k][3]);
            }
        }
        float* cf = selbuf(cfsel);
#pragma unroll
        for (int k = 0; k < 12; k++) {
            int m = tmm + 8 * k;
            if (m < NODE) {
                float g = gm_[m];
                size_t row = (size_t)(b * NODE + m);
                float4 o = make_float4(acc[k][0] * g, acc[k][1] * g,
                                       acc[k][2] * g, acc[k][3] * g);
                *(float4*)&outF[row * 512 + tc4] = o;
                *(float4*)&cf[row * HID + tc4] = o;
            }
        }
    }
}

// ---------------------------------------------------------------------------
extern "C" void kernel_launch(void* const* d_in, const int* in_sizes, int n_in,
                              void* d_out, int out_size, void* d_ws, size_t ws_size,
                              hipStream_t stream) {
    const float* x_sc = (const float*)d_in[0];
    const void* e_sc = d_in[1];
    const float* x_fc = (const float*)d_in[2];
    const void* e_fc = d_in[3];
    const float* W0 = (const float*)d_in[4];
    const float* b0 = (const float*)d_in[5];
    const float* W1 = (const float*)d_in[6];
    const float* b1 = (const float*)d_in[7];
    const float* Wa = (const float*)d_in[8];

    float* out = (float*)d_out;
    size_t os = (size_t)NN * 512;
    float* x1s = out;
    float* x2s = out + os;
    float* x1f = out + 2 * os;
    float* x2f = out + 3 * os;

    const int RB = NN / BM;               // 360 row-blocks per side

    k_detect<<<1, 64, 0, stream>>>(e_sc);
    k_zero_adj<<<2048, 256, 0, stream>>>();
    k_build_adj<<<1024, 256, 0, stream>>>(e_sc, 0);
    k_build_adj<<<1024, 256, 0, stream>>>(e_fc, 1);
    k_norm_adj<<<NB, 128, 0, stream>>>(0);
    k_norm_adj<<<NB, 128, 0, stream>>>(1);

    // ---- layer 1: fused S/F  T = [x_sc; x_fc] @ W0 ----
    k_gemm_tile<<<RB * 4, 256, 0, stream>>>(x_sc, x_fc, -1, -1, -1, -1,
                                            NODE, NODE, W0, RB);
    k_agg2<<<2048, 256, 0, stream>>>(b0, /*hs/hf*/0, x1s, x1f);

    // ---- co-attention 1: T2 = hs @ Wa (M=N, side A only) ----
    k_gemm_tile<<<RB * 2, 256, 0, stream>>>(nullptr, nullptr, 0, -1, 0, -1,
                                            HID, HID, Wa, RB);
    k_coatt<<<NB, CO_THREADS, 0, stream>>>(/*hf*/1, /*hs*/0, x1s + HID, x1f + HID, 2, 3);

    // ---- layer 2: fused S/F  T = [hs|cs ; hf|cf] @ W1 (K=512) ----
    k_gemm_tile<<<RB * 4, 256, 0, stream>>>(nullptr, nullptr, 0, 2, 1, 3,
                                            512, HID, W1, RB);
    k_agg2<<<2048, 256, 0, stream>>>(b1, /*hs2/hf2*/0, x2s, x2f);

    // ---- co-attention 2 ----
    k_gemm_tile<<<RB * 2, 256, 0, stream>>>(nullptr, nullptr, 0, -1, 0, -1,
                                            HID, HID, Wa, RB);
    k_coatt<<<NB, CO_THREADS, 0, stream>>>(/*hf2*/1, /*hs2*/0, x2s + HID, x2f + HID, 2, 3);
}

// Round 11
// 1452.732 us; speedup vs baseline: 1.1786x; 1.1786x over previous
//
#include <hip/hip_runtime.h>
#include <hip/hip_bf16.h>
#include <math.h>

#define NODE 90
#define HID 256
#define NB 512
#define NN (NB * NODE)
#define EDGES (NB * 2700)

__device__ __forceinline__ float tanh_safe(float s) {
    s = fminf(fmaxf(s, -15.f), 15.f);
    float t = __expf(2.f * s);
    return (t - 1.f) / (t + 1.f);
}

// ---------------------------------------------------------------------------
// Module-scope fp32 scratch. d_ws unused.
// ---------------------------------------------------------------------------
__device__ float g_adjS[(size_t)NB * NODE * NODE];
__device__ float g_adjF[(size_t)NB * NODE * NODE];
__device__ float g_T[(size_t)2 * NN * HID];          // 2N rows (S then F)
__device__ float g_hs[(size_t)NN * HID];
__device__ float g_hf[(size_t)NN * HID];
__device__ float g_cs[(size_t)NN * HID];
__device__ float g_cf[(size_t)NN * HID];
__device__ int g_flags[2];

__device__ __forceinline__ float* adjPtr(int w) { return w ? g_adjF : g_adjS; }
__device__ __forceinline__ float* selbuf(int w) {
    switch (w) {
        case 0: return g_hs;
        case 1: return g_hf;
        case 2: return g_cs;
        default: return g_cf;
    }
}

// ---------------------------------------------------------------------------
__global__ void k_detect(const void* edges) {
    if (threadIdx.x != 0 || blockIdx.x != 0) return;
    const int* ei = (const int*)edges;
    int odd_nonzero = 0;
    for (int i = 0; i < 2048; i += 2)
        if (ei[i + 1] != 0) odd_nonzero = 1;
    g_flags[1] = odd_nonzero ? 0 : 1;
}

__global__ void k_zero_adj() {
    size_t n = (size_t)NB * NODE * NODE;
    size_t stride = (size_t)gridDim.x * blockDim.x;
    for (size_t i = (size_t)blockIdx.x * blockDim.x + threadIdx.x; i < n; i += stride) {
        g_adjS[i] = 0.f;
        g_adjF[i] = 0.f;
    }
}

// ---------------------------------------------------------------------------
__global__ void k_build_adj(const void* __restrict__ edges, int which) {
    float* adj = adjPtr(which);
    int e64 = g_flags[1];
    const int* e32 = (const int*)edges;
    const long long* e64p = (const long long*)edges;
    int i = blockIdx.x * blockDim.x + threadIdx.x;
    int stride = gridDim.x * blockDim.x;
    for (; i < EDGES; i += stride) {
        long long s, d;
        if (e64) { s = e64p[i]; d = e64p[EDGES + i]; }
        else     { s = e32[i];  d = e32[EDGES + i]; }
        if (s < 0 || s >= NN || d < 0 || d >= NN) continue;
        int b = (int)(d / NODE);
        if ((int)(s / NODE) != b) continue;
        atomicAdd(&adj[(size_t)b * NODE * NODE +
                       (size_t)((int)d - b * NODE) * NODE + ((int)s - b * NODE)], 1.0f);
    }
}

// ---------------------------------------------------------------------------
__global__ void k_norm_adj(int which) {
    float* A = adjPtr(which) + (size_t)blockIdx.x * NODE * NODE;
    __shared__ float dinv[NODE];
    int tid = threadIdx.x;
    if (tid < NODE) {
        float s = 0.f;
        for (int k = 0; k < NODE; k++) s += A[tid * NODE + k];
        dinv[tid] = (s > 0.f) ? rsqrtf(s) : 0.f;
    }
    __syncthreads();
    for (int i = tid; i < NODE * NODE; i += blockDim.x) {
        int d = i / NODE;
        int s = i - d * NODE;
        A[i] *= dinv[d] * dinv[s];
    }
}

// ---------------------------------------------------------------------------
// Tiled fp32 GEMM: g_T[tbase+row][c] = X(row) @ W.
// X = Xext (ldx_ext) or selbuf(x1sel) [+ selbuf(x2sel) for cols 256.. K=512].
// Tile 64x128, BK=16, 256 threads, 4x8 micro-tile. Grid = (M/64)*2.
// As/Bs stored staggered (col c -> c + 4*(c>>5)) => 2-way bank quads.
// ---------------------------------------------------------------------------
#define BM 64
#define BN 128
#define BKc 16
__global__ __launch_bounds__(256) void k_gemm_tile(const float* __restrict__ Xext,
                                                   int x1sel, int x2sel,
                                                   int K, int ldx_ext,
                                                   const float* __restrict__ W,
                                                   int tbase) {
    __shared__ float As[BKc][72];    // phys col: r + 4*(r>>5), max 67
    __shared__ float Bs[BKc][140];   // phys col: c + 4*(c>>5), max 139
    int tid = threadIdx.x;
    int id = blockIdx.x;
    int bm = id >> 1, bn = id & 1;
    int r0 = bm * BM, c0 = bn * BN;
    int ti = tid & 15, tj = tid >> 4;

    float acc[4][8];
#pragma unroll
    for (int i = 0; i < 4; i++)
#pragma unroll
        for (int j = 0; j < 8; j++) acc[i][j] = 0.f;

    for (int k0 = 0; k0 < K; k0 += BKc) {
        int kl = K - k0; if (kl > BKc) kl = BKc;
        const float* Xs; int xc, ldx;
        if (x1sel < 0)                    { Xs = Xext;           xc = k0;       ldx = ldx_ext; }
        else if (x2sel >= 0 && k0 >= HID) { Xs = selbuf(x2sel);  xc = k0 - HID; ldx = HID; }
        else                              { Xs = selbuf(x1sel);  xc = k0;       ldx = HID; }

        __syncthreads();
        // stage A: 64x16 = 1024 elems, 4 per thread
#pragma unroll
        for (int q = 0; q < 4; q++) {
            int i = tid + (q << 8);
            int r = i >> 4, kk = i & 15;
            As[kk][r + 4 * (r >> 5)] =
                (kk < kl) ? Xs[(size_t)(r0 + r) * ldx + xc + kk] : 0.f;
        }
        // stage B: 16x128 = 512 float4, 2 per thread
#pragma unroll
        for (int q = 0; q < 2; q++) {
            int i = tid + (q << 8);
            int kk = i >> 5, c4 = (i & 31) << 2;
            float4 v = make_float4(0.f, 0.f, 0.f, 0.f);
            if (kk < kl) v = *(const float4*)&W[(size_t)(k0 + kk) * HID + c0 + c4];
            *(float4*)&Bs[kk][c4 + 4 * (c4 >> 5)] = v;
        }
        __syncthreads();

#pragma unroll
        for (int kk = 0; kk < BKc; kk++) {
            float4 a0 = *(const float4*)&As[kk][4 * ti + 4 * (ti >> 3)];
            float4 b0 = *(const float4*)&Bs[kk][8 * tj + 4 * (tj >> 2)];
            float4 b1 = *(const float4*)&Bs[kk][8 * tj + 4 + 4 * ((8 * tj + 4) >> 5)];
            float av[4] = {a0.x, a0.y, a0.z, a0.w};
            float bv[8] = {b0.x, b0.y, b0.z, b0.w, b1.x, b1.y, b1.z, b1.w};
#pragma unroll
            for (int i = 0; i < 4; i++)
#pragma unroll
                for (int j = 0; j < 8; j++)
                    acc[i][j] = fmaf(av[i], bv[j], acc[i][j]);
        }
    }

#pragma unroll
    for (int i = 0; i < 4; i++) {
        size_t r = (size_t)(tbase + r0 + 4 * ti + i);
        float4 o0 = make_float4(acc[i][0], acc[i][1], acc[i][2], acc[i][3]);
        float4 o1 = make_float4(acc[i][4], acc[i][5], acc[i][6], acc[i][7]);
        *(float4*)&g_T[r * HID + c0 + 8 * tj] = o0;
        *(float4*)&g_T[r * HID + c0 + 8 * tj + 4] = o1;
    }
}

// ---------------------------------------------------------------------------
// Fused two-stream aggregate. grid = 2048: side = idx>=1024, graph = (idx&1023)>>1,
// col-half = idx&1.  out = relu(Adj @ T + bias) -> selbuf(hsel0+side) + out x-cols.
// ---------------------------------------------------------------------------
__global__ __launch_bounds__(256) void k_agg2(const float* __restrict__ bias,
                                              int hsel0, float* __restrict__ outS,
                                              float* __restrict__ outF) {
    __shared__ float AdjT[NODE][102];
    int tid = threadIdx.x;
    int idx = blockIdx.x;
    int side = idx >> 10;
    int b = (idx & 1023) >> 1;
    int c0 = (idx & 1) * 128;
    const float* Adj = adjPtr(side) + (size_t)b * NODE * NODE;
    const float* Tg = g_T + ((size_t)side * NN + (size_t)b * NODE) * HID;
    float* outp = side ? outF : outS;
    float* hdst = selbuf(hsel0 + side);

    for (int i = tid; i < NODE * NODE; i += 256) {
        int n = i / NODE, k = i - n * NODE;
        AdjT[k][n] = Adj[i];
    }
    for (int i = tid; i < NODE * 12; i += 256) {
        int k = i / 12, n = NODE + (i % 12);
        AdjT[k][n] = 0.f;
    }
    __syncthreads();

    int ti = tid & 15, tj = tid >> 4;
    int rbase = 6 * ti;
    int cc = c0 + 8 * tj;

    float acc[6][8];
#pragma unroll
    for (int i = 0; i < 6; i++)
#pragma unroll
        for (int j = 0; j < 8; j++) acc[i][j] = 0.f;

#pragma unroll 2
    for (int k = 0; k < NODE; k++) {
        float4 t0 = *(const float4*)&Tg[(size_t)k * HID + cc];
        float4 t1 = *(const float4*)&Tg[(size_t)k * HID + cc + 4];
        float bv[8] = {t0.x, t0.y, t0.z, t0.w, t1.x, t1.y, t1.z, t1.w};
        float2 a01 = *(const float2*)&AdjT[k][rbase];
        float2 a23 = *(const float2*)&AdjT[k][rbase + 2];
        float2 a45 = *(const float2*)&AdjT[k][rbase + 4];
        float av[6] = {a01.x, a01.y, a23.x, a23.y, a45.x, a45.y};
#pragma unroll
        for (int i = 0; i < 6; i++)
#pragma unroll
            for (int j = 0; j < 8; j++)
                acc[i][j] = fmaf(av[i], bv[j], acc[i][j]);
    }

    float bb[8];
#pragma unroll
    for (int j = 0; j < 8; j++) bb[j] = bias[cc + j];

#pragma unroll
    for (int i = 0; i < 6; i++) {
        int n = rbase + i;
        if (n < NODE) {
            size_t row = (size_t)(b * NODE + n);
            float v[8];
#pragma unroll
            for (int j = 0; j < 8; j++) v[j] = fmaxf(acc[i][j] + bb[j], 0.f);
            float4 o0 = make_float4(v[0], v[1], v[2], v[3]);
            float4 o1 = make_float4(v[4], v[5], v[6], v[7]);
            *(float4*)&hdst[row * HID + cc] = o0;
            *(float4*)&hdst[row * HID + cc + 4] = o1;
            *(float4*)&outp[row * 512 + cc] = o0;
            *(float4*)&outp[row * 512 + cc + 4] = o1;
        }
    }
}

// ---------------------------------------------------------------------------
// Fused co-attention per graph (unchanged — verified).
// ---------------------------------------------------------------------------
#define CO_THREADS 512
__global__ __launch_bounds__(CO_THREADS, 1) void k_coatt(int hfsel, int hssel,
                                                         float* __restrict__ outS,
                                                         float* __restrict__ outF,
                                                         int cssel, int cfsel) {
    __shared__ float hfl[NODE][258];
    __shared__ float Pm[NODE][92];
    __shared__ float t2s[NODE][34];
    __shared__ float rmax_[NODE], rinv_[NODE], fn_[NODE], gm_[NODE];

    int b = blockIdx.x;
    int tid = threadIdx.x;
    const float* HF = selbuf(hfsel) + (size_t)b * NODE * HID;
    const float* HS = selbuf(hssel) + (size_t)b * NODE * HID;
    const float* T2 = g_T + (size_t)b * NODE * HID;

    for (int i = tid; i < NODE * 64; i += CO_THREADS) {
        int n = i >> 6, c4 = (i & 63) << 2;
        *(float4*)&hfl[n][c4] = *(const float4*)&HF[(size_t)n * HID + c4];
    }

    {
        const int tm = tid & 31;
        const int tn5 = tid >> 5;
        const float* hr0 = hfl[tm];
        const float* hr1 = hfl[tm + 32];
        const float* hr2 = hfl[(tm < 26) ? tm + 64 : 0];
        const float* tr[6];
#pragma unroll
        for (int k = 0; k < 6; k++) {
            int n = tn5 + 16 * k;
            tr[k] = t2s[(n < NODE) ? n : 0];
        }
        float at[3][6];
#pragma unroll
        for (int i = 0; i < 3; i++)
#pragma unroll
            for (int k = 0; k < 6; k++) at[i][k] = 0.f;

        for (int d0 = 0; d0 < HID; d0 += 32) {
            __syncthreads();
            for (int i = tid; i < NODE * 32; i += CO_THREADS) {
                int n = i >> 5, dd = i & 31;
                t2s[n][dd] = T2[(size_t)n * HID + d0 + dd];
            }
            __syncthreads();
#pragma unroll
            for (int dd = 0; dd < 32; dd += 2) {
                float2 a0 = *(const float2*)&hr0[d0 + dd];
                float2 a1 = *(const float2*)&hr1[d0 + dd];
                float2 a2 = *(const float2*)&hr2[d0 + dd];
#pragma unroll
                for (int k = 0; k < 6; k++) {
                    float2 bk = *(const float2*)&tr[k][dd];
                    at[0][k] = fmaf(a0.x, bk.x, at[0][k]);
                    at[0][k] = fmaf(a0.y, bk.y, at[0][k]);
                    at[1][k] = fmaf(a1.x, bk.x, at[1][k]);
                    at[1][k] = fmaf(a1.y, bk.y, at[1][k]);
                    at[2][k] = fmaf(a2.x, bk.x, at[2][k]);
                    at[2][k] = fmaf(a2.y, bk.y, at[2][k]);
                }
            }
        }
        __syncthreads();
        int mv[3] = {tm, tm + 32, tm + 64};
#pragma unroll
        for (int i = 0; i < 3; i++) {
            if (mv[i] < NODE) {
#pragma unroll
                for (int k = 0; k < 6; k++) {
                    int n = tn5 + 16 * k;
                    if (n < NODE) Pm[n][mv[i]] = tanh_safe(at[i][k]);
                }
            }
        }
    }
    __syncthreads();

    if (tid < NODE) {
        int n = tid;
        float mx = -2.f;
        for (int m = 0; m < NODE; m++) mx = fmaxf(mx, Pm[n][m]);
        float s = 0.f;
        for (int m = 0; m < NODE; m++) s += __expf(Pm[n][m] - mx);
        rmax_[n] = mx;
        rinv_[n] = 1.f / s;
        fn_[n] = s * __expf(mx);
    } else if (tid >= 256 && tid < 256 + NODE) {
        int m = tid - 256;
        float mx = -2.f;
        for (int n = 0; n < NODE; n++) mx = fmaxf(mx, Pm[n][m]);
        float s = 0.f;
        for (int n = 0; n < NODE; n++) s += __expf(Pm[n][m] - mx);
        gm_[m] = __expf(-mx) / s;
    }
    __syncthreads();

    for (int i = tid; i < NODE * NODE; i += CO_THREADS) {
        int n = i / NODE, m = i - n * NODE;
        Pm[n][m] = __expf(Pm[n][m] - rmax_[n]) * rinv_[n];
    }
    __syncthreads();

    {
        const int tc4 = (tid & 63) << 2;
        const int tnn = tid >> 6;
        int nrow[12];
#pragma unroll
        for (int k = 0; k < 12; k++) {
            int n = tnn + 8 * k;
            nrow[k] = (n < NODE) ? n : 0;
        }
        float acc[12][4];
#pragma unroll
        for (int k = 0; k < 12; k++)
#pragma unroll
            for (int j = 0; j < 4; j++) acc[k][j] = 0.f;

#pragma unroll 2
        for (int m = 0; m < NODE; m++) {
            float4 h = *(const float4*)&hfl[m][tc4];
#pragma unroll
            for (int k = 0; k < 12; k++) {
                float p = Pm[nrow[k]][m];
                acc[k][0] = fmaf(p, h.x, acc[k][0]);
                acc[k][1] = fmaf(p, h.y, acc[k][1]);
                acc[k][2] = fmaf(p, h.z, acc[k][2]);
                acc[k][3] = fmaf(p, h.w, acc[k][3]);
            }
        }
        float* cs = selbuf(cssel);
#pragma unroll
        for (int k = 0; k < 12; k++) {
            int n = tnn + 8 * k;
            if (n < NODE) {
                size_t row = (size_t)(b * NODE + n);
                float4 o = make_float4(acc[k][0], acc[k][1], acc[k][2], acc[k][3]);
                *(float4*)&outS[row * 512 + tc4] = o;
                *(float4*)&cs[row * HID + tc4] = o;
            }
        }
    }
    __syncthreads();

    for (int i = tid; i < NODE * 64; i += CO_THREADS) {
        int n = i >> 6, c4 = (i & 63) << 2;
        *(float4*)&hfl[n][c4] = *(const float4*)&HS[(size_t)n * HID + c4];
    }
    for (int i = tid; i < NODE * NODE; i += CO_THREADS) {
        int n = i / NODE, m = i - n * NODE;
        Pm[n][m] *= fn_[n];
    }
    __syncthreads();

    {
        const int tc4 = (tid & 63) << 2;
        const int tmm = tid >> 6;
        int mrow[12];
#pragma unroll
        for (int k = 0; k < 12; k++) {
            int m = tmm + 8 * k;
            mrow[k] = (m < NODE) ? m : 0;
        }
        float acc[12][4];
#pragma unroll
        for (int k = 0; k < 12; k++)
#pragma unroll
            for (int j = 0; j < 4; j++) acc[k][j] = 0.f;

#pragma unroll 2
        for (int n = 0; n < NODE; n++) {
            float4 h = *(const float4*)&hfl[n][tc4];
#pragma unroll
            for (int k = 0; k < 12; k++) {
                float p = Pm[n][mrow[k]];
                acc[k][0] = fmaf(p, h.x, acc[k][0]);
                acc[k][1] = fmaf(p, h.y, acc[k][1]);
                acc[k][2] = fmaf(p, h.z, acc[k][2]);
                acc[k][3] = fmaf(p, h.w, acc[k][3]);
            }
        }
        float* cf = selbuf(cfsel);
#pragma unroll
        for (int k = 0; k < 12; k++) {
            int m = tmm + 8 * k;
            if (m < NODE) {
                float g = gm_[m];
                size_t row = (size_t)(b * NODE + m);
                float4 o = make_float4(acc[k][0] * g, acc[k][1] * g,
                                       acc[k][2] * g, acc[k][3] * g);
                *(float4*)&outF[row * 512 + tc4] = o;
                *(float4*)&cf[row * HID + tc4] = o;
            }
        }
    }
}

// ---------------------------------------------------------------------------
extern "C" void kernel_launch(void* const* d_in, const int* in_sizes, int n_in,
                              void* d_out, int out_size, void* d_ws, size_t ws_size,
                              hipStream_t stream) {
    const float* x_sc = (const float*)d_in[0];
    const void* e_sc = d_in[1];
    const float* x_fc = (const float*)d_in[2];
    const void* e_fc = d_in[3];
    const float* W0 = (const float*)d_in[4];
    const float* b0 = (const float*)d_in[5];
    const float* W1 = (const float*)d_in[6];
    const float* b1 = (const float*)d_in[7];
    const float* Wa = (const float*)d_in[8];

    float* out = (float*)d_out;
    size_t os = (size_t)NN * 512;
    float* x1s = out;
    float* x2s = out + os;
    float* x1f = out + 2 * os;
    float* x2f = out + 3 * os;

    const int GRID = (NN / BM) * 2;       // 1440 blocks per GEMM dispatch

    k_detect<<<1, 64, 0, stream>>>(e_sc);
    k_zero_adj<<<2048, 256, 0, stream>>>();
    k_build_adj<<<1024, 256, 0, stream>>>(e_sc, 0);
    k_build_adj<<<1024, 256, 0, stream>>>(e_fc, 1);
    k_norm_adj<<<NB, 128, 0, stream>>>(0);
    k_norm_adj<<<NB, 128, 0, stream>>>(1);

    // ---- layer 1: T_S = x_sc @ W0 (rows 0..N), T_F = x_fc @ W0 (rows N..2N) ----
    k_gemm_tile<<<GRID, 256, 0, stream>>>(x_sc, -1, -1, NODE, NODE, W0, 0);
    k_gemm_tile<<<GRID, 256, 0, stream>>>(x_fc, -1, -1, NODE, NODE, W0, NN);
    k_agg2<<<2048, 256, 0, stream>>>(b0, /*hs/hf*/0, x1s, x1f);

    // ---- co-attention 1: T2 = hs @ Wa (rows 0..N) ----
    k_gemm_tile<<<GRID, 256, 0, stream>>>(nullptr, 0, -1, HID, HID, Wa, 0);
    k_coatt<<<NB, CO_THREADS, 0, stream>>>(/*hf*/1, /*hs*/0, x1s + HID, x1f + HID, 2, 3);

    // ---- layer 2: T_S = [hs|cs] @ W1, T_F = [hf|cf] @ W1 (K=512) ----
    k_gemm_tile<<<GRID, 256, 0, stream>>>(nullptr, 0, 2, 512, HID, W1, 0);
    k_gemm_tile<<<GRID, 256, 0, stream>>>(nullptr, 1, 3, 512, HID, W1, NN);
    k_agg2<<<2048, 256, 0, stream>>>(b1, /*hs2/hf2*/0, x2s, x2f);

    // ---- co-attention 2 ----
    k_gemm_tile<<<GRID, 256, 0, stream>>>(nullptr, 0, -1, HID, HID, Wa, 0);
    k_coatt<<<NB, CO_THREADS, 0, stream>>>(/*hf2*/1, /*hs2*/0, x2s + HID, x2f + HID, 2, 3);
}